// Round 2
// 1037.614 us; speedup vs baseline: 1.0699x; 1.0699x over previous
//
#include <hip/hip_runtime.h>

typedef unsigned int uint;
typedef unsigned short ushort;

typedef __bf16 bf16x8 __attribute__((ext_vector_type(8)));
typedef float f32x4 __attribute__((ext_vector_type(4)));

// All d_in / d_out tensors are FP32 (per reference). Compute path is bf16
// MFMA with fp32 accumulation; x/weights are converted to bf16 up front.
__device__ __forceinline__ float bflo(uint u) { return __uint_as_float(u << 16); }
__device__ __forceinline__ float bfhi(uint u) { return __uint_as_float(u & 0xffff0000u); }
__device__ __forceinline__ ushort f2bf(float f) {
  uint u = __float_as_uint(f);
  u += 0x7fffu + ((u >> 16) & 1u);
  return (ushort)(u >> 16);
}
__device__ __forceinline__ uint pack2(float lo, float hi) {
  return (uint)f2bf(lo) | ((uint)f2bf(hi) << 16);
}

// ---------------------------------------------------------------------------
// fp32 -> bf16 elementwise cast (8 elem/thread)
// ---------------------------------------------------------------------------
__global__ __launch_bounds__(256) void cvt_f32_bf16(
    const float* __restrict__ in, ushort* __restrict__ out)
{
  const long i = ((long)blockIdx.x * 256 + threadIdx.x) * 8;
  float4 a = *(const float4*)(in + i);
  float4 b = *(const float4*)(in + i + 4);
  uint4 r;
  r.x = pack2(a.x, a.y); r.y = pack2(a.z, a.w);
  r.z = pack2(b.x, b.y); r.w = pack2(b.z, b.w);
  *(uint4*)(out + i) = r;
}

// ---------------------------------------------------------------------------
// fused transpose + fp32->bf16 cast: out[C,R](bf16) = in[R,C](fp32)^T
// ---------------------------------------------------------------------------
__global__ __launch_bounds__(256) void transpose_wf(
    const float* __restrict__ in, ushort* __restrict__ out, int R, int Ccols)
{
  __shared__ float tile[32][33];
  const int tx = threadIdx.x, ty = threadIdx.y;
  const int c0 = blockIdx.x * 32, r0 = blockIdx.y * 32;
#pragma unroll
  for (int j = 0; j < 32; j += 8)
    tile[ty + j][tx] = in[(long)(r0 + ty + j) * Ccols + (c0 + tx)];
  __syncthreads();
#pragma unroll
  for (int j = 0; j < 32; j += 8)
    out[(long)(c0 + ty + j) * R + (r0 + tx)] = f2bf(tile[tx][ty + j]);
}

// ---------------------------------------------------------------------------
// GEMM: C[M,N] = A[M,K](bf16) @ Bt[N,K](bf16)^T + bias[N](fp32); optional relu;
// output bf16 or fp32 (out_f32 flag). m97 structure: 128x128 tile, BK=64,
// 4 waves (2x2), 4x4 mfma_f32_16x16x32_bf16, global_load_lds width-16 staging.
// Epilogue stages the C tile through LDS (reusing As/Bs) for full-line
// coalesced dwordx4 stores; blockIdx is XCD-chunk swizzled for A-strip L2 reuse.
// ---------------------------------------------------------------------------
#define BM 128
#define BN 128
#define BKK 64
#define CSTR 136  // bf16 C-stage row stride (ushorts): 272B rows, 16B aligned
#define FSTR 132  // f32  C-stage row stride (floats):  528B rows, 16B aligned

__global__ __launch_bounds__(256, 2) void gemm_bt(
    const ushort* __restrict__ A, const ushort* __restrict__ Bt,
    const float* __restrict__ bias, void* __restrict__ Cv,
    int M, int N, int K, int relu, int out_f32)
{
  // union: K-loop uses As(16KB)+Bs(16KB); epilogue reuses all of it as C stage.
  __shared__ ushort smem[17408];  // 34816 B
  ushort* As = smem;
  ushort* Bs = smem + BM * BKK;
  const int t = threadIdx.x;
  const int w = t >> 6, l = t & 63;
  const int quad = l >> 4, l16 = l & 15;
  const int wm = w & 1, wn = w >> 1;

  // XCD-chunked swizzle: hw ids round-robin over 8 XCDs; remap so each XCD
  // owns a contiguous run of logical tiles (same A-strip across N-tiles).
  const int gx = gridDim.x;
  int bid = blockIdx.y * gx + blockIdx.x;
  const int nwg = gx * gridDim.y;
  if ((nwg & 7) == 0) bid = (bid & 7) * (nwg >> 3) + (bid >> 3);
  const long m0 = (long)(bid / gx) * BM;
  const long n0 = (long)(bid % gx) * BN;

  const int srow = l >> 3;       // row within 8-row chunk (8 lanes * 16B = one 128B row)
  const int scol = (l & 7) * 8;  // element col within BK

  f32x4 acc[4][4];
#pragma unroll
  for (int i = 0; i < 4; ++i)
#pragma unroll
    for (int j = 0; j < 4; ++j)
      acc[i][j] = f32x4{0.f, 0.f, 0.f, 0.f};

  for (int k0 = 0; k0 < K; k0 += BKK) {
#pragma unroll
    for (int i = 0; i < 4; ++i) {
      const int chunk = w * 4 + i;       // wave-uniform: 16 chunks of 1KB
      const int row = chunk * 8 + srow;  // 0..127
      const ushort* ga = A + (m0 + row) * (long)K + k0 + scol;
      const ushort* gb = Bt + (n0 + row) * (long)K + k0 + scol;
      __builtin_amdgcn_global_load_lds(
          (const __attribute__((address_space(1))) uint*)ga,
          (__attribute__((address_space(3))) uint*)(As + chunk * 512), 16, 0, 0);
      __builtin_amdgcn_global_load_lds(
          (const __attribute__((address_space(1))) uint*)gb,
          (__attribute__((address_space(3))) uint*)(Bs + chunk * 512), 16, 0, 0);
    }
    __syncthreads();  // drains vmcnt before s_barrier
#pragma unroll
    for (int ks = 0; ks < 2; ++ks) {
      bf16x8 af[4], bfr[4];
#pragma unroll
      for (int im = 0; im < 4; ++im)
        af[im] = *(const bf16x8*)(As + (wm * 64 + im * 16 + l16) * BKK + ks * 32 + quad * 8);
#pragma unroll
      for (int in = 0; in < 4; ++in)
        bfr[in] = *(const bf16x8*)(Bs + (wn * 64 + in * 16 + l16) * BKK + ks * 32 + quad * 8);
#pragma unroll
      for (int im = 0; im < 4; ++im)
#pragma unroll
        for (int in = 0; in < 4; ++in)
          acc[im][in] = __builtin_amdgcn_mfma_f32_16x16x32_bf16(af[im], bfr[in], acc[im][in], 0, 0, 0);
    }
    __syncthreads();
  }

  // epilogue: C/D layout col=lane&15, row=quad*4+reg (verified m89/m91).
  // After the loop's trailing barrier all waves are done with As/Bs -> reuse
  // as C-stage so global stores are full-line dwordx4 instead of 2B scatters.
  if (!out_f32) {
    ushort* Ct = smem;  // [128][CSTR]
#pragma unroll
    for (int in = 0; in < 4; ++in) {
      const int cl = wn * 64 + in * 16 + l16;
      const float bv = bias[n0 + cl];
#pragma unroll
      for (int im = 0; im < 4; ++im) {
        const int rl = wm * 64 + im * 16 + quad * 4;
#pragma unroll
        for (int r = 0; r < 4; ++r) {
          float vv = acc[im][in][r] + bv;
          if (relu) vv = fmaxf(vv, 0.f);
          Ct[(rl + r) * CSTR + cl] = f2bf(vv);
        }
      }
    }
    __syncthreads();
    ushort* Cb = (ushort*)Cv;
#pragma unroll
    for (int it = 0; it < 8; ++it) {
      const int idx = it * 256 + t;        // 2048 x 16B chunks = 32KB tile
      const int row = idx >> 4, c16 = idx & 15;  // 128 rows x 16 chunks
      uint4 d = *(const uint4*)(Ct + row * CSTR + c16 * 8);
      *(uint4*)(Cb + (m0 + row) * (long)N + n0 + c16 * 8) = d;
    }
  } else {
    float* Cf4 = (float*)smem;  // [64][FSTR] per half
    float* Cg = (float*)Cv;
#pragma unroll
    for (int half = 0; half < 2; ++half) {
      if (wm == half) {
#pragma unroll
        for (int in = 0; in < 4; ++in) {
          const int cl = wn * 64 + in * 16 + l16;
          const float bv = bias[n0 + cl];
#pragma unroll
          for (int im = 0; im < 4; ++im) {
            const int rl = im * 16 + quad * 4;  // 0..63 within half
#pragma unroll
            for (int r = 0; r < 4; ++r) {
              float vv = acc[im][in][r] + bv;
              if (relu) vv = fmaxf(vv, 0.f);
              Cf4[(rl + r) * FSTR + cl] = vv;
            }
          }
        }
      }
      __syncthreads();
#pragma unroll
      for (int it = 0; it < 8; ++it) {
        const int idx = it * 256 + t;      // 2048 x float4 = 32KB half-tile
        const int row = idx >> 5, c4 = idx & 31;  // 64 rows x 32 chunks
        float4 d = *(const float4*)(Cf4 + row * FSTR + c4 * 4);
        *(float4*)(Cg + (m0 + half * 64 + row) * (long)N + n0 + c4 * 4) = d;
      }
      __syncthreads();  // half-tile drained before next pass overwrites
    }
  }
}

// ---------------------------------------------------------------------------
// MFMA window attention. One block per (b, window): 32 rows x 8 heads x 64 dh.
// 4 waves; wave w handles heads 2w, 2w+1. Phase 1: k staged in LDS, QK^T via
// mfma_16x16x32 (q frags from global), softmax in C-layout (shfl over 16-lane
// col group), P -> LDS (C-layout -> A-layout transform). Phase 2: v restaged
// over the k buffer, PV via mfma, O assembled in the P buffer (stride 72,
// 16B-aligned rows), coalesced dwordx4 store in place over q.
// ---------------------------------------------------------------------------
__global__ __launch_bounds__(256, 2) void attn_mfma(
    ushort* qo, const ushort* __restrict__ k, const ushort* __restrict__ v)
{
  __shared__ ushort kv[32 * 512];     // 32 KB: k in phase 1, v in phase 2
  __shared__ ushort pbuf[8][32 * 72]; // per (wave,head): P then O; 36 KB
  const int t = threadIdx.x;
  const int w = t >> 6, l = t & 63;
  const int quad = l >> 4, l16 = l & 15;
  const long base = (long)blockIdx.x * (32 * 512);

  // stage k -> kv (32 chunks of 1 KB = one 512-elem row each; wave-uniform base)
#pragma unroll
  for (int i = 0; i < 8; ++i) {
    const int c = w * 8 + i;
    __builtin_amdgcn_global_load_lds(
        (const __attribute__((address_space(1))) uint*)(k + base + c * 512 + l * 8),
        (__attribute__((address_space(3))) uint*)(kv + c * 512), 16, 0, 0);
  }
  // q fragments from global (A-layout: row=l16, k=quad*8+j), overlap k-stage
  bf16x8 qf[2][2][2];  // [hh][mt][ks]
#pragma unroll
  for (int hh = 0; hh < 2; ++hh) {
    const int h = w * 2 + hh;
#pragma unroll
    for (int mt = 0; mt < 2; ++mt)
#pragma unroll
      for (int ks = 0; ks < 2; ++ks)
        qf[hh][mt][ks] = *(const bf16x8*)(qo + base + (mt * 16 + l16) * 512 + h * 64 + ks * 32 + quad * 8);
  }
  __syncthreads();

  // QK^T + softmax + P->LDS, per head
#pragma unroll
  for (int hh = 0; hh < 2; ++hh) {
    const int h = w * 2 + hh;
    f32x4 sc[2][2];
#pragma unroll
    for (int mt = 0; mt < 2; ++mt)
#pragma unroll
      for (int nt = 0; nt < 2; ++nt)
        sc[mt][nt] = f32x4{0.f, 0.f, 0.f, 0.f};
#pragma unroll
    for (int ks = 0; ks < 2; ++ks) {
      // B-frag: B[k][n] = kmat[n][k] -> contiguous 8 elems of k-row n=l16
      bf16x8 kb0 = *(const bf16x8*)(kv + (0 * 16 + l16) * 512 + h * 64 + ks * 32 + quad * 8);
      bf16x8 kb1 = *(const bf16x8*)(kv + (1 * 16 + l16) * 512 + h * 64 + ks * 32 + quad * 8);
      sc[0][0] = __builtin_amdgcn_mfma_f32_16x16x32_bf16(qf[hh][0][ks], kb0, sc[0][0], 0, 0, 0);
      sc[0][1] = __builtin_amdgcn_mfma_f32_16x16x32_bf16(qf[hh][0][ks], kb1, sc[0][1], 0, 0, 0);
      sc[1][0] = __builtin_amdgcn_mfma_f32_16x16x32_bf16(qf[hh][1][ks], kb0, sc[1][0], 0, 0, 0);
      sc[1][1] = __builtin_amdgcn_mfma_f32_16x16x32_bf16(qf[hh][1][ks], kb1, sc[1][1], 0, 0, 0);
    }
    ushort* pb = pbuf[w * 2 + hh];
#pragma unroll
    for (int mt = 0; mt < 2; ++mt) {
#pragma unroll
      for (int r = 0; r < 4; ++r) {
        // row = mt*16 + quad*4 + r; cols nt*16+l16 (C-layout)
        float a = sc[mt][0][r] * 0.125f;  // 1/sqrt(64)
        float b = sc[mt][1][r] * 0.125f;
        float mx = fmaxf(a, b);
        mx = fmaxf(mx, __shfl_xor(mx, 1));
        mx = fmaxf(mx, __shfl_xor(mx, 2));
        mx = fmaxf(mx, __shfl_xor(mx, 4));
        mx = fmaxf(mx, __shfl_xor(mx, 8));
        float ea = __expf(a - mx), eb = __expf(b - mx);
        float s = ea + eb;
        s += __shfl_xor(s, 1);
        s += __shfl_xor(s, 2);
        s += __shfl_xor(s, 4);
        s += __shfl_xor(s, 8);
        const float inv = 1.f / s;
        const int row = mt * 16 + quad * 4 + r;
        pb[row * 72 + 0 * 16 + l16] = f2bf(ea * inv);
        pb[row * 72 + 1 * 16 + l16] = f2bf(eb * inv);
      }
    }
  }
  __syncthreads();  // all waves done reading k

  // stage v over kv
#pragma unroll
  for (int i = 0; i < 8; ++i) {
    const int c = w * 8 + i;
    __builtin_amdgcn_global_load_lds(
        (const __attribute__((address_space(1))) uint*)(v + base + c * 512 + l * 8),
        (__attribute__((address_space(3))) uint*)(kv + c * 512), 16, 0, 0);
  }
  // P A-frags (A-layout: row=l16+mt*16, k=quad*8+j); rows are 144B -> 16B aligned
  bf16x8 pf[2][2];  // [hh][mt]
#pragma unroll
  for (int hh = 0; hh < 2; ++hh)
#pragma unroll
    for (int mt = 0; mt < 2; ++mt)
      pf[hh][mt] = *(const bf16x8*)(pbuf[w * 2 + hh] + (mt * 16 + l16) * 72 + quad * 8);
  __syncthreads();  // v staged

#pragma unroll
  for (int hh = 0; hh < 2; ++hh) {
    const int h = w * 2 + hh;
    f32x4 oc[2][4];
#pragma unroll
    for (int mt = 0; mt < 2; ++mt)
#pragma unroll
      for (int nt = 0; nt < 4; ++nt)
        oc[mt][nt] = f32x4{0.f, 0.f, 0.f, 0.f};
#pragma unroll
    for (int nt = 0; nt < 4; ++nt) {
      // B-frag for V: B[k][n] = V[quad*8+j][h*64+nt*16+l16] (column gather)
      bf16x8 bv;
#pragma unroll
      for (int j = 0; j < 8; ++j)
        bv[j] = ((const __bf16*)kv)[(quad * 8 + j) * 512 + h * 64 + nt * 16 + l16];
      oc[0][nt] = __builtin_amdgcn_mfma_f32_16x16x32_bf16(pf[hh][0], bv, oc[0][nt], 0, 0, 0);
      oc[1][nt] = __builtin_amdgcn_mfma_f32_16x16x32_bf16(pf[hh][1], bv, oc[1][nt], 0, 0, 0);
    }
    // O -> pbuf (C-layout scatter; quad row-step 4*144B = 16 banks -> 2-way, free)
    ushort* pb = pbuf[w * 2 + hh];
#pragma unroll
    for (int mt = 0; mt < 2; ++mt)
#pragma unroll
      for (int nt = 0; nt < 4; ++nt)
#pragma unroll
        for (int r = 0; r < 4; ++r)
          pb[(mt * 16 + quad * 4 + r) * 72 + nt * 16 + l16] = f2bf(oc[mt][nt][r]);
  }

  // coalesced O store: per wave 2 heads x 32 rows x 64 cols (8 KB), in place over q.
  // Same-wave pbuf data -> no barrier needed (lgkmcnt ordering suffices).
#pragma unroll
  for (int i = 0; i < 8; ++i) {
    const int idx = i * 64 + l;           // 0..511 16B-chunks
    const int hh = idx >> 8;
    const int row = (idx >> 3) & 31;
    const int c8 = idx & 7;
    uint4 d = *(const uint4*)(pbuf[w * 2 + hh] + row * 72 + c8 * 8);
    *(uint4*)(qo + base + row * 512 + (w * 2 + hh) * 64 + c8 * 8) = d;
  }
}

// ---------------------------------------------------------------------------
// ln1: x1(bf16) = LayerNorm(a(bf16) + b(bf16)) * g + be   (rows of 512)
// one wave per row, 4 rows/block
// ---------------------------------------------------------------------------
__global__ __launch_bounds__(256, 4) void ln1_res(
    const ushort* __restrict__ a, const ushort* __restrict__ b,
    const float* __restrict__ g, const float* __restrict__ be,
    ushort* __restrict__ out)
{
  const long row = (long)blockIdx.x * 4 + (threadIdx.x >> 6);
  const int lane = threadIdx.x & 63;
  const long off = row * 512 + lane * 8;
  uint4 ua = *(const uint4*)(a + off);
  uint4 ub = *(const uint4*)(b + off);
  float x[8];
  x[0] = bflo(ua.x) + bflo(ub.x); x[1] = bfhi(ua.x) + bfhi(ub.x);
  x[2] = bflo(ua.y) + bflo(ub.y); x[3] = bfhi(ua.y) + bfhi(ub.y);
  x[4] = bflo(ua.z) + bflo(ub.z); x[5] = bfhi(ua.z) + bfhi(ub.z);
  x[6] = bflo(ua.w) + bflo(ub.w); x[7] = bfhi(ua.w) + bfhi(ub.w);
  float sum = 0.f;
#pragma unroll
  for (int i = 0; i < 8; ++i) sum += x[i];
#pragma unroll
  for (int i = 1; i < 64; i <<= 1) sum += __shfl_xor(sum, i, 64);
  const float mu = sum * (1.0f / 512.0f);
  float vsum = 0.f;
#pragma unroll
  for (int i = 0; i < 8; ++i) { const float d = x[i] - mu; vsum += d * d; }
#pragma unroll
  for (int i = 1; i < 64; i <<= 1) vsum += __shfl_xor(vsum, i, 64);
  const float rs = rsqrtf(vsum * (1.0f / 512.0f) + 1e-5f);
  float4 g0 = *(const float4*)(g + lane * 8);
  float4 g1v = *(const float4*)(g + lane * 8 + 4);
  float4 e0 = *(const float4*)(be + lane * 8);
  float4 e1 = *(const float4*)(be + lane * 8 + 4);
  uint4 r;
  r.x = pack2((x[0] - mu) * rs * g0.x + e0.x, (x[1] - mu) * rs * g0.y + e0.y);
  r.y = pack2((x[2] - mu) * rs * g0.z + e0.z, (x[3] - mu) * rs * g0.w + e0.w);
  r.z = pack2((x[4] - mu) * rs * g1v.x + e1.x, (x[5] - mu) * rs * g1v.y + e1.y);
  r.w = pack2((x[6] - mu) * rs * g1v.z + e1.z, (x[7] - mu) * rs * g1v.w + e1.w);
  *(uint4*)(out + off) = r;
}

// ---------------------------------------------------------------------------
// ln2: out(fp32) = LayerNorm(x1(bf16) + ff(fp32)) * g + be; ff aliases out
// (in-place per-thread: reads complete before writes) -> no __restrict__ on ff/out
// ---------------------------------------------------------------------------
__global__ __launch_bounds__(256, 4) void ln2_res(
    const ushort* __restrict__ a, const float* bff,
    const float* __restrict__ g, const float* __restrict__ be,
    float* out)
{
  const long row = (long)blockIdx.x * 4 + (threadIdx.x >> 6);
  const int lane = threadIdx.x & 63;
  const long off = row * 512 + lane * 8;
  uint4 ua = *(const uint4*)(a + off);
  float4 fa = *(const float4*)(bff + off);
  float4 fb = *(const float4*)(bff + off + 4);
  float x[8];
  x[0] = bflo(ua.x) + fa.x; x[1] = bfhi(ua.x) + fa.y;
  x[2] = bflo(ua.y) + fa.z; x[3] = bfhi(ua.y) + fa.w;
  x[4] = bflo(ua.z) + fb.x; x[5] = bfhi(ua.z) + fb.y;
  x[6] = bflo(ua.w) + fb.z; x[7] = bfhi(ua.w) + fb.w;
  float sum = 0.f;
#pragma unroll
  for (int i = 0; i < 8; ++i) sum += x[i];
#pragma unroll
  for (int i = 1; i < 64; i <<= 1) sum += __shfl_xor(sum, i, 64);
  const float mu = sum * (1.0f / 512.0f);
  float vsum = 0.f;
#pragma unroll
  for (int i = 0; i < 8; ++i) { const float d = x[i] - mu; vsum += d * d; }
#pragma unroll
  for (int i = 1; i < 64; i <<= 1) vsum += __shfl_xor(vsum, i, 64);
  const float rs = rsqrtf(vsum * (1.0f / 512.0f) + 1e-5f);
  float4 g0 = *(const float4*)(g + lane * 8);
  float4 g1v = *(const float4*)(g + lane * 8 + 4);
  float4 e0 = *(const float4*)(be + lane * 8);
  float4 e1 = *(const float4*)(be + lane * 8 + 4);
  float4 r0, r1;
  r0.x = (x[0] - mu) * rs * g0.x + e0.x;
  r0.y = (x[1] - mu) * rs * g0.y + e0.y;
  r0.z = (x[2] - mu) * rs * g0.z + e0.z;
  r0.w = (x[3] - mu) * rs * g0.w + e0.w;
  r1.x = (x[4] - mu) * rs * g1v.x + e1.x;
  r1.y = (x[5] - mu) * rs * g1v.y + e1.y;
  r1.z = (x[6] - mu) * rs * g1v.z + e1.z;
  r1.w = (x[7] - mu) * rs * g1v.w + e1.w;
  *(float4*)(out + off) = r0;
  *(float4*)(out + off + 4) = r1;
}

// ---------------------------------------------------------------------------
extern "C" void kernel_launch(void* const* d_in, const int* in_sizes, int n_in,
                              void* d_out, int out_size, void* d_ws, size_t ws_size,
                              hipStream_t stream)
{
  const float* x   = (const float*)d_in[0];
  const float* Wq  = (const float*)d_in[1];
  const float* bq  = (const float*)d_in[2];
  const float* Wk  = (const float*)d_in[3];
  const float* bk  = (const float*)d_in[4];
  const float* Wv  = (const float*)d_in[5];
  const float* bv  = (const float*)d_in[6];
  const float* Wo  = (const float*)d_in[7];
  const float* bo  = (const float*)d_in[8];
  const float* g1  = (const float*)d_in[9];
  const float* be1 = (const float*)d_in[10];
  const float* W1  = (const float*)d_in[11];
  const float* b1  = (const float*)d_in[12];
  const float* W2  = (const float*)d_in[13];
  const float* b2  = (const float*)d_in[14];
  const float* g2  = (const float*)d_in[15];
  const float* be2 = (const float*)d_in[16];

  const long M = 65536;               // 8 * 8192 rows
  const size_t SZ = (size_t)M * 512;  // one [M,512] activation (elements)

  // ws (bf16 units): [xb | R0 | Wqt Wkt Wvt Wot W1t W2t]  -> 134 MiB total
  ushort* wsb = (ushort*)d_ws;
  ushort* xb  = wsb;            // bf16(x); reused as FFN h buffer later
  ushort* R0  = wsb + SZ;       // q -> o -> x1
  ushort* Wqt = wsb + 2 * SZ;
  ushort* Wkt = Wqt + 512 * 512;
  ushort* Wvt = Wkt + 512 * 512;
  ushort* Wot = Wvt + 512 * 512;
  ushort* W1t = Wot + 512 * 512;   // [2048][512]
  ushort* W2t = W1t + 512 * 2048;  // [512][2048]

  // d_out (128 MiB fp32) doubles as bf16 scratch before its final contents:
  // k -> bytes [0,64M), v -> bytes [64M,128M), then attn_out over k region.
  ushort* outb = (ushort*)d_out;
  ushort* kb = outb;
  ushort* vb = outb + SZ;
  float* outf = (float*)d_out;

  dim3 tb(32, 8);
  transpose_wf<<<dim3(16, 16), tb, 0, stream>>>(Wq, Wqt, 512, 512);
  transpose_wf<<<dim3(16, 16), tb, 0, stream>>>(Wk, Wkt, 512, 512);
  transpose_wf<<<dim3(16, 16), tb, 0, stream>>>(Wv, Wvt, 512, 512);
  transpose_wf<<<dim3(16, 16), tb, 0, stream>>>(Wo, Wot, 512, 512);
  transpose_wf<<<dim3(64, 16), tb, 0, stream>>>(W1, W1t, 512, 2048);
  transpose_wf<<<dim3(16, 64), tb, 0, stream>>>(W2, W2t, 2048, 512);
  cvt_f32_bf16<<<dim3(16384), dim3(256), 0, stream>>>(x, xb);

  dim3 blk(256);
  // QKV projections (bf16 in, bf16 out)
  gemm_bt<<<dim3(4, 512), blk, 0, stream>>>(xb, Wqt, bq, R0, 65536, 512, 512, 0, 0);
  gemm_bt<<<dim3(4, 512), blk, 0, stream>>>(xb, Wkt, bk, kb, 65536, 512, 512, 0, 0);
  gemm_bt<<<dim3(4, 512), blk, 0, stream>>>(xb, Wvt, bv, vb, 65536, 512, 512, 0, 0);
  // window attention (MFMA): o overwrites q in R0
  attn_mfma<<<dim3(2048), blk, 0, stream>>>(R0, kb, vb);
  // attn_out = o @ Wo + bo -> outb[0,SZ) (k is dead)
  gemm_bt<<<dim3(4, 512), blk, 0, stream>>>(R0, Wot, bo, outb, 65536, 512, 512, 0, 0);
  // x1 = LN(x + attn_out) -> R0 (o is dead); x read as bf16 xb
  ln1_res<<<dim3(16384), blk, 0, stream>>>(xb, outb, g1, be1, R0);
  // FFN in 4 row-chunks of 16384; h (bf16) fills xb exactly (16384*2048 = SZ);
  // ff (fp32) written straight into d_out rows (k/v/attn_out all dead).
  for (int c = 0; c < 4; ++c) {
    const size_t rows0 = (size_t)c * 16384;
    gemm_bt<<<dim3(16, 128), blk, 0, stream>>>(R0 + rows0 * 512, W1t, b1, xb,
                                               16384, 2048, 512, 1, 0);
    gemm_bt<<<dim3(4, 128), blk, 0, stream>>>(xb, W2t, b2, outf + rows0 * 512,
                                              16384, 512, 2048, 0, 1);
  }
  // out = LN(x1 + ff) -> fp32, in place over ff
  ln2_res<<<dim3(16384), blk, 0, stream>>>(R0, outf, g2, be2, outf);
}